// Round 1
// baseline (1583.714 us; speedup 1.0000x reference)
//
#include <hip/hip_runtime.h>
#include <math.h>

#define N_NODES 50000
#define N_EDGES 800000
#define FEATS 128
#define NCLASS 2
#define TN 8   // nodes per block in node kernel

// ---------------- Edge scatter: sum[dst] += in_feat[src], deg[dst] += 1 ------
// 32 lanes per edge, 1 float4 per lane (128 floats/row).
__global__ __launch_bounds__(256) void edge_scatter(
    const float* __restrict__ x, const int* __restrict__ src,
    const int* __restrict__ dst, float* __restrict__ sum, float* __restrict__ deg)
{
    long long gid = (long long)blockIdx.x * blockDim.x + threadIdx.x;
    int e = (int)(gid >> 5);
    if (e >= N_EDGES) return;
    int l = (int)(gid & 31);
    int s = src[e];
    int d = dst[e];
    const float4 g = *(const float4*)(x + (size_t)s * FEATS + l * 4);
    float* p = sum + (size_t)d * FEATS + l * 4;
    atomicAdd(p + 0, g.x);
    atomicAdd(p + 1, g.y);
    atomicAdd(p + 2, g.z);
    atomicAdd(p + 3, g.w);
    if (l == 0) atomicAdd(deg + d, 1.0f);
}

// ---------------- Fused node kernel: h = relu(x@Ws^T + (sum/deg)@Wn^T + b),
//                  out = sigmoid(h@Wfc^T + bfc) --------------------------------
// 128 threads/block, TN nodes/block. Thread t owns output feature o = t and
// reads W rows contiguously (float4); x/h_neigh tiles staged in LDS (broadcast
// reads, conflict-free).
__global__ __launch_bounds__(128) void node_fused(
    const float* __restrict__ x, const float* __restrict__ sum,
    const float* __restrict__ deg,
    const float* __restrict__ Wself, const float* __restrict__ Wneigh,
    const float* __restrict__ bneigh,
    const float* __restrict__ Wfc, const float* __restrict__ bfc,
    float* __restrict__ out)
{
    __shared__ float xs[TN][FEATS];
    __shared__ float hs[TN][FEATS];
    __shared__ float rdeg[TN];
    __shared__ float partial[TN][NCLASS][2];

    const int t = threadIdx.x;
    const int base = blockIdx.x * TN;

    if (t < TN) {
        int node = base + t;
        float dv = (node < N_NODES) ? deg[node] : 1.0f;
        rdeg[t] = 1.0f / fmaxf(dv, 1.0f);
    }
    __syncthreads();

    // Stage x and h_neigh tiles.
    for (int i = t; i < TN * FEATS; i += 128) {
        int n = i >> 7, k = i & 127;
        int node = base + n;
        if (node < N_NODES) {
            xs[n][k] = x[(size_t)node * FEATS + k];
            hs[n][k] = sum[(size_t)node * FEATS + k] * rdeg[n];
        } else {
            xs[n][k] = 0.0f;
            hs[n][k] = 0.0f;
        }
    }
    __syncthreads();

    float acc[TN];
#pragma unroll
    for (int n = 0; n < TN; n++) acc[n] = 0.0f;

    const float4* Ws = (const float4*)(Wself + (size_t)t * FEATS);
    const float4* Wn = (const float4*)(Wneigh + (size_t)t * FEATS);
#pragma unroll 4
    for (int k4 = 0; k4 < FEATS / 4; k4++) {
        float4 ws = Ws[k4];
        float4 wn = Wn[k4];
        int k = k4 * 4;
#pragma unroll
        for (int n = 0; n < TN; n++) {
            float a = acc[n];
            a += ws.x * xs[n][k + 0];
            a += ws.y * xs[n][k + 1];
            a += ws.z * xs[n][k + 2];
            a += ws.w * xs[n][k + 3];
            a += wn.x * hs[n][k + 0];
            a += wn.y * hs[n][k + 1];
            a += wn.z * hs[n][k + 2];
            a += wn.w * hs[n][k + 3];
            acc[n] = a;
        }
    }

    const float bn = bneigh[t];
    const float wf0 = Wfc[t];
    const float wf1 = Wfc[FEATS + t];
    const int lane = t & 63;
    const int wave = t >> 6;

#pragma unroll
    for (int n = 0; n < TN; n++) {
        float h = fmaxf(acc[n] + bn, 0.0f);
        float p0 = h * wf0;
        float p1 = h * wf1;
#pragma unroll
        for (int off = 32; off > 0; off >>= 1) {
            p0 += __shfl_down(p0, off);
            p1 += __shfl_down(p1, off);
        }
        if (lane == 0) {
            partial[n][0][wave] = p0;
            partial[n][1][wave] = p1;
        }
    }
    __syncthreads();

    if (t < TN * NCLASS) {
        int n = t >> 1, c = t & 1;
        int node = base + n;
        if (node < N_NODES) {
            float z = partial[n][c][0] + partial[n][c][1] + bfc[c];
            out[(size_t)node * NCLASS + c] = 1.0f / (1.0f + expf(-z));
        }
    }
}

extern "C" void kernel_launch(void* const* d_in, const int* in_sizes, int n_in,
                              void* d_out, int out_size, void* d_ws, size_t ws_size,
                              hipStream_t stream) {
    const float* in_feat = (const float*)d_in[0];
    const int*   src     = (const int*)d_in[1];
    const int*   dst     = (const int*)d_in[2];
    const float* Wself   = (const float*)d_in[3];
    const float* Wneigh  = (const float*)d_in[4];
    const float* bneigh  = (const float*)d_in[5];
    const float* Wfc     = (const float*)d_in[6];
    const float* bfc     = (const float*)d_in[7];
    float* out = (float*)d_out;

    float* sum = (float*)d_ws;                          // [N_NODES][FEATS]
    float* deg = sum + (size_t)N_NODES * FEATS;         // [N_NODES]

    size_t zero_bytes = (size_t)N_NODES * FEATS * sizeof(float)
                      + (size_t)N_NODES * sizeof(float);
    hipMemsetAsync(d_ws, 0, zero_bytes, stream);

    long long edge_threads = (long long)N_EDGES * 32;
    int eb = (int)((edge_threads + 255) / 256);
    edge_scatter<<<eb, 256, 0, stream>>>(in_feat, src, dst, sum, deg);

    int nb = (N_NODES + TN - 1) / TN;
    node_fused<<<nb, 128, 0, stream>>>(in_feat, sum, deg, Wself, Wneigh,
                                       bneigh, Wfc, bfc, out);
}

// Round 2
// 455.502 us; speedup vs baseline: 3.4769x; 3.4769x over previous
//
#include <hip/hip_runtime.h>
#include <math.h>

#define N_NODES 50000
#define N_EDGES 800000
#define FEATS 128
#define NCLASS 2
#define TN 8      // nodes per block in node kernel
#define SCAN_T 1024

// ---------- 1. degree histogram (int atomics, L2-resident counters) ----------
__global__ __launch_bounds__(256) void hist_deg(
    const int* __restrict__ dst, int* __restrict__ degi)
{
    int e = blockIdx.x * 256 + threadIdx.x;
    if (e < N_EDGES) atomicAdd(&degi[dst[e]], 1);
}

// ---------- 2. single-block exclusive scan over 50K degrees ------------------
__global__ __launch_bounds__(SCAN_T) void scan_offsets(
    const int* __restrict__ degi, int* __restrict__ offs, int* __restrict__ cursor)
{
    __shared__ int part[SCAN_T];
    const int t = threadIdx.x;
    const int CH = (N_NODES + SCAN_T - 1) / SCAN_T;   // 49
    const int lo = t * CH;
    const int hi = (lo + CH < N_NODES) ? lo + CH : N_NODES;

    int s = 0;
    for (int i = lo; i < hi; i++) s += degi[i];
    part[t] = s;
    __syncthreads();

    // Hillis-Steele inclusive scan of per-thread partials
    for (int off = 1; off < SCAN_T; off <<= 1) {
        int v = part[t];
        int u = (t >= off) ? part[t - off] : 0;
        __syncthreads();
        part[t] = v + u;
        __syncthreads();
    }

    int run = (t > 0) ? part[t - 1] : 0;   // exclusive prefix of this chunk
    for (int i = lo; i < hi; i++) {
        offs[i] = run;
        cursor[i] = run;
        run += degi[i];
    }
    if (t == SCAN_T - 1) offs[N_NODES] = run;   // == N_EDGES
}

// ---------- 3. scatter src into per-dst buckets ------------------------------
__global__ __launch_bounds__(256) void scatter_idx(
    const int* __restrict__ src, const int* __restrict__ dst,
    int* __restrict__ cursor, int* __restrict__ eidx)
{
    int e = blockIdx.x * 256 + threadIdx.x;
    if (e < N_EDGES) {
        int pos = atomicAdd(&cursor[dst[e]], 1);
        eidx[pos] = src[e];
    }
}

// ---------- 4. per-node gather + mean (no float atomics) ---------------------
// One wave per node. Lane l owns columns 2l, 2l+1 (float2 = 8B/lane,
// 512B/wave per gathered row, fully coalesced). x table (25.6 MB) is L2/L3
// resident, so the random row gathers are cache reads, not HBM.
__global__ __launch_bounds__(256) void gather_mean(
    const float* __restrict__ x, const int* __restrict__ eidx,
    const int* __restrict__ offs, float* __restrict__ hneigh)
{
    int node = blockIdx.x * 4 + (threadIdx.x >> 6);
    if (node >= N_NODES) return;
    const int l = threadIdx.x & 63;
    const int beg = offs[node];
    const int end = offs[node + 1];

    float2 acc0 = {0.f, 0.f}, acc1 = {0.f, 0.f};
    int e = beg;
    for (; e + 1 < end; e += 2) {
        int s0 = eidx[e];
        int s1 = eidx[e + 1];
        const float2 v0 = *(const float2*)(x + (size_t)s0 * FEATS + l * 2);
        const float2 v1 = *(const float2*)(x + (size_t)s1 * FEATS + l * 2);
        acc0.x += v0.x; acc0.y += v0.y;
        acc1.x += v1.x; acc1.y += v1.y;
    }
    if (e < end) {
        int s0 = eidx[e];
        const float2 v0 = *(const float2*)(x + (size_t)s0 * FEATS + l * 2);
        acc0.x += v0.x; acc0.y += v0.y;
    }

    const int cnt = end - beg;
    const float r = 1.0f / fmaxf((float)cnt, 1.0f);
    float2 o;
    o.x = (acc0.x + acc1.x) * r;
    o.y = (acc0.y + acc1.y) * r;
    *(float2*)(hneigh + (size_t)node * FEATS + l * 2) = o;
}

// ---------- 5. fused node kernel ---------------------------------------------
// h = relu(x@Ws^T + hneigh@Wn^T + b); out = sigmoid(h@Wfc^T + bfc)
// 128 threads/block, TN nodes/block. Thread t owns output feature o = t,
// reads W rows contiguously (float4); x/hneigh tiles in LDS, read as float4
// broadcasts (same address across all threads -> conflict-free ds_read_b128).
__global__ __launch_bounds__(128) void node_fused(
    const float* __restrict__ x, const float* __restrict__ hneigh,
    const float* __restrict__ Wself, const float* __restrict__ Wneigh,
    const float* __restrict__ bneigh,
    const float* __restrict__ Wfc, const float* __restrict__ bfc,
    float* __restrict__ out)
{
    __shared__ float xs[TN][FEATS];
    __shared__ float hs[TN][FEATS];
    __shared__ float partial[TN][NCLASS][2];

    const int t = threadIdx.x;
    const int base = blockIdx.x * TN;

    for (int i = t; i < TN * FEATS; i += 128) {
        int n = i >> 7, k = i & 127;
        int node = base + n;
        if (node < N_NODES) {
            xs[n][k] = x[(size_t)node * FEATS + k];
            hs[n][k] = hneigh[(size_t)node * FEATS + k];
        } else {
            xs[n][k] = 0.0f;
            hs[n][k] = 0.0f;
        }
    }
    __syncthreads();

    float acc[TN];
#pragma unroll
    for (int n = 0; n < TN; n++) acc[n] = 0.0f;

    const float4* Ws = (const float4*)(Wself + (size_t)t * FEATS);
    const float4* Wn = (const float4*)(Wneigh + (size_t)t * FEATS);
#pragma unroll 4
    for (int k4 = 0; k4 < FEATS / 4; k4++) {
        float4 ws = Ws[k4];
        float4 wn = Wn[k4];
        int k = k4 * 4;
#pragma unroll
        for (int n = 0; n < TN; n++) {
            float4 xv = *(const float4*)&xs[n][k];
            float4 hv = *(const float4*)&hs[n][k];
            float a = acc[n];
            a += ws.x * xv.x; a += ws.y * xv.y;
            a += ws.z * xv.z; a += ws.w * xv.w;
            a += wn.x * hv.x; a += wn.y * hv.y;
            a += wn.z * hv.z; a += wn.w * hv.w;
            acc[n] = a;
        }
    }

    const float bn = bneigh[t];
    const float wf0 = Wfc[t];
    const float wf1 = Wfc[FEATS + t];
    const int lane = t & 63;
    const int wave = t >> 6;

#pragma unroll
    for (int n = 0; n < TN; n++) {
        float h = fmaxf(acc[n] + bn, 0.0f);
        float p0 = h * wf0;
        float p1 = h * wf1;
#pragma unroll
        for (int off = 32; off > 0; off >>= 1) {
            p0 += __shfl_down(p0, off);
            p1 += __shfl_down(p1, off);
        }
        if (lane == 0) {
            partial[n][0][wave] = p0;
            partial[n][1][wave] = p1;
        }
    }
    __syncthreads();

    if (t < TN * NCLASS) {
        int n = t >> 1, c = t & 1;
        int node = base + n;
        if (node < N_NODES) {
            float z = partial[n][c][0] + partial[n][c][1] + bfc[c];
            out[(size_t)node * NCLASS + c] = 1.0f / (1.0f + expf(-z));
        }
    }
}

extern "C" void kernel_launch(void* const* d_in, const int* in_sizes, int n_in,
                              void* d_out, int out_size, void* d_ws, size_t ws_size,
                              hipStream_t stream) {
    const float* in_feat = (const float*)d_in[0];
    const int*   src     = (const int*)d_in[1];
    const int*   dst     = (const int*)d_in[2];
    const float* Wself   = (const float*)d_in[3];
    const float* Wneigh  = (const float*)d_in[4];
    const float* bneigh  = (const float*)d_in[5];
    const float* Wfc     = (const float*)d_in[6];
    const float* bfc     = (const float*)d_in[7];
    float* out = (float*)d_out;

    // Workspace layout (int region padded to 16B for the float region)
    int* degi   = (int*)d_ws;                    // [N_NODES]
    int* offs   = degi + N_NODES;                // [N_NODES+1]
    int* cursor = offs + N_NODES + 1;            // [N_NODES]
    int* eidx   = cursor + N_NODES;              // [N_EDGES]
    size_t int_elems = (size_t)N_NODES * 3 + 1 + N_EDGES;   // 950001
    int_elems = (int_elems + 3) & ~(size_t)3;               // 950004 -> 16B aligned
    float* hneigh = (float*)d_ws + int_elems;    // [N_NODES][FEATS]

    // zero only the degree counters
    hipMemsetAsync(d_ws, 0, (size_t)N_NODES * sizeof(int), stream);

    int eb = (N_EDGES + 255) / 256;
    hist_deg<<<eb, 256, 0, stream>>>(dst, degi);
    scan_offsets<<<1, SCAN_T, 0, stream>>>(degi, offs, cursor);
    scatter_idx<<<eb, 256, 0, stream>>>(src, dst, cursor, eidx);

    int gb = (N_NODES + 3) / 4;   // 4 waves/block, 1 wave/node
    gather_mean<<<gb, 256, 0, stream>>>(in_feat, eidx, offs, hneigh);

    int nb = (N_NODES + TN - 1) / TN;
    node_fused<<<nb, 128, 0, stream>>>(in_feat, hneigh, Wself, Wneigh,
                                       bneigh, Wfc, bfc, out);
}

// Round 3
// 333.449 us; speedup vs baseline: 4.7495x; 1.3660x over previous
//
#include <hip/hip_runtime.h>
#include <math.h>

#define N_NODES 50000
#define N_EDGES 800000
#define FEATS 128
#define KTOT 256
#define NCLASS 2
#define SCAN_T 1024

typedef __attribute__((ext_vector_type(8))) short bf16x8;
typedef __attribute__((ext_vector_type(4))) float f32x4;

__device__ __forceinline__ float bflo(unsigned u) {
    return __uint_as_float(u << 16);
}
__device__ __forceinline__ float bfhi(unsigned u) {
    return __uint_as_float(u & 0xffff0000u);
}
// round-to-nearest-even f32 -> bf16 (inputs finite)
__device__ __forceinline__ unsigned f2bf(float f) {
    unsigned u = __float_as_uint(f);
    return (u + 0x7fffu + ((u >> 16) & 1u)) >> 16;
}

// ---------- 1. fused prep: cast x->bf16, cast [Ws|Wn]->bf16 Wcat[N][K],
//                degree histogram (all independent) -------------------------
#define CASTX_BLOCKS 3125   // 6.4M floats / (256 thr * 8)
#define HIST_BLOCKS  3125   // 800000 / 256
#define CASTW_BLOCKS 64     // 32768 elems / (256 thr * 2)

__global__ __launch_bounds__(256) void prep(
    const float* __restrict__ x, const int* __restrict__ dst,
    const float* __restrict__ Ws, const float* __restrict__ Wn,
    unsigned short* __restrict__ xh, unsigned short* __restrict__ wcat,
    int* __restrict__ degi)
{
    int b = blockIdx.x;
    if (b < CASTX_BLOCKS) {
        size_t i = ((size_t)b * 256 + threadIdx.x) * 8;
        float4 v0 = *(const float4*)(x + i);
        float4 v1 = *(const float4*)(x + i + 4);
        uint4 o;
        o.x = f2bf(v0.x) | (f2bf(v0.y) << 16);
        o.y = f2bf(v0.z) | (f2bf(v0.w) << 16);
        o.z = f2bf(v1.x) | (f2bf(v1.y) << 16);
        o.w = f2bf(v1.z) | (f2bf(v1.w) << 16);
        *(uint4*)(xh + i) = o;
    } else if (b < CASTX_BLOCKS + HIST_BLOCKS) {
        int e = (b - CASTX_BLOCKS) * 256 + threadIdx.x;
        if (e < N_EDGES) atomicAdd(&degi[dst[e]], 1);
    } else {
        int i = (b - CASTX_BLOCKS - HIST_BLOCKS) * 512 + threadIdx.x * 2;
        int n = i >> 8, k = i & 255;          // k is even
        float a0 = (k < 128) ? Ws[n * 128 + k] : Wn[n * 128 + k - 128];
        float a1 = (k + 1 < 128) ? Ws[n * 128 + k + 1] : Wn[n * 128 + k + 1 - 128];
        *(unsigned*)(wcat + i) = f2bf(a0) | (f2bf(a1) << 16);
    }
}

// ---------- 2. single-block exclusive scan over degrees ---------------------
__global__ __launch_bounds__(SCAN_T) void scan_offsets(
    const int* __restrict__ degi, int* __restrict__ offs, int* __restrict__ cursor)
{
    __shared__ int part[SCAN_T];
    const int t = threadIdx.x;
    const int CH = (N_NODES + SCAN_T - 1) / SCAN_T;   // 49
    const int lo = t * CH;
    const int hi = (lo + CH < N_NODES) ? lo + CH : N_NODES;

    int s = 0;
    for (int i = lo; i < hi; i++) s += degi[i];
    part[t] = s;
    __syncthreads();

    for (int off = 1; off < SCAN_T; off <<= 1) {
        int v = part[t];
        int u = (t >= off) ? part[t - off] : 0;
        __syncthreads();
        part[t] = v + u;
        __syncthreads();
    }

    int run = (t > 0) ? part[t - 1] : 0;
    for (int i = lo; i < hi; i++) {
        offs[i] = run;
        cursor[i] = run;
        run += degi[i];
    }
    if (t == SCAN_T - 1) offs[N_NODES] = run;
}

// ---------- 3. scatter src into per-dst buckets ------------------------------
__global__ __launch_bounds__(256) void scatter_idx(
    const int* __restrict__ src, const int* __restrict__ dst,
    int* __restrict__ cursor, int* __restrict__ eidx)
{
    int e = blockIdx.x * 256 + threadIdx.x;
    if (e < N_EDGES) {
        int pos = atomicAdd(&cursor[dst[e]], 1);
        eidx[pos] = src[e];
    }
}

// ---------- 4. per-node gather + mean over bf16 rows -------------------------
// One wave per node, lane owns 1 uint (2 bf16 cols). 256 B/row coalesced.
__global__ __launch_bounds__(256) void gather_mean(
    const unsigned* __restrict__ xh32, const int* __restrict__ eidx,
    const int* __restrict__ offs, unsigned* __restrict__ hh32)
{
    int node = blockIdx.x * 4 + (threadIdx.x >> 6);
    if (node >= N_NODES) return;
    const int l = threadIdx.x & 63;
    const int beg = offs[node];
    const int end = offs[node + 1];

    float s0 = 0.f, s1 = 0.f, t0 = 0.f, t1 = 0.f;
    int e = beg;
    for (; e + 3 < end; e += 4) {
        unsigned u0 = xh32[(size_t)eidx[e]     * 64 + l];
        unsigned u1 = xh32[(size_t)eidx[e + 1] * 64 + l];
        unsigned u2 = xh32[(size_t)eidx[e + 2] * 64 + l];
        unsigned u3 = xh32[(size_t)eidx[e + 3] * 64 + l];
        s0 += bflo(u0) + bflo(u1);
        s1 += bfhi(u0) + bfhi(u1);
        t0 += bflo(u2) + bflo(u3);
        t1 += bfhi(u2) + bfhi(u3);
    }
    for (; e < end; e++) {
        unsigned u = xh32[(size_t)eidx[e] * 64 + l];
        s0 += bflo(u);
        s1 += bfhi(u);
    }
    const float r = 1.0f / fmaxf((float)(end - beg), 1.0f);
    hh32[(size_t)node * 64 + l] = f2bf((s0 + t0) * r) | (f2bf((s1 + t1) * r) << 16);
}

// ---------- 5. node MFMA: h=relu([xh|hh]@Wcat^T+bn); out=sigmoid(h@Wfc^T+bfc)
// 4 waves/block, 32 nodes/wave, 128 nodes/block. A = [nodes][K] row-major
// (xh k<128, hh k>=128); B = Wcat [N][K] (B^T layout, m91 recipe). Per lane:
// a/b frags are 8 contiguous bf16 at row (l&15), k-chunk (l>>4)*8.
// D: col = l&15 (feat), row = (l>>4)*4 + reg (node) [m89-verified].
__global__ __launch_bounds__(256) void node_mfma(
    const unsigned short* __restrict__ xh, const unsigned short* __restrict__ hh,
    const unsigned short* __restrict__ wcat,
    const float* __restrict__ bn, const float* __restrict__ wfc,
    const float* __restrict__ bfc, float* __restrict__ out)
{
    const int wid = threadIdx.x >> 6;
    const int l = threadIdx.x & 63;
    const int node0 = blockIdx.x * 128 + wid * 32;
    const int fr = l & 15, fq = l >> 4;

    // epilogue constants for this lane's 8 feature columns
    float bnv[8], w0v[8], w1v[8];
#pragma unroll
    for (int nt = 0; nt < 8; nt++) {
        int f = nt * 16 + fr;
        bnv[nt] = bn[f];
        w0v[nt] = wfc[f];
        w1v[nt] = wfc[FEATS + f];
    }

    f32x4 acc[2][8] = {};   // [row-tile][n-tile]

#pragma unroll
    for (int ks = 0; ks < 8; ks++) {
        const unsigned short* abase = (ks < 4) ? xh : hh;
        const int ka = (ks & 3) * 32 + fq * 8;     // k within the 128-wide half
        const int kb = ks * 32 + fq * 8;           // k within full K=256

        bf16x8 bfr[8];
#pragma unroll
        for (int nt = 0; nt < 8; nt++) {
            int n = nt * 16 + fr;
            bfr[nt] = *(const bf16x8*)(wcat + (size_t)n * KTOT + kb);
        }
#pragma unroll
        for (int rt = 0; rt < 2; rt++) {
            int row = node0 + rt * 16 + fr;
            row = (row < N_NODES) ? row : N_NODES - 1;   // clamp; dup rows, stores guarded
            bf16x8 afr = *(const bf16x8*)(abase + (size_t)row * FEATS + ka);
#pragma unroll
            for (int nt = 0; nt < 8; nt++)
                acc[rt][nt] = __builtin_amdgcn_mfma_f32_16x16x32_bf16(
                    afr, bfr[nt], acc[rt][nt], 0, 0, 0);
        }
    }

    const float b0 = bfc[0], b1 = bfc[1];
#pragma unroll
    for (int rt = 0; rt < 2; rt++) {
        float p0[4] = {0, 0, 0, 0}, p1[4] = {0, 0, 0, 0};
#pragma unroll
        for (int nt = 0; nt < 8; nt++) {
#pragma unroll
            for (int r = 0; r < 4; r++) {
                float h = fmaxf(acc[rt][nt][r] + bnv[nt], 0.f);
                p0[r] += h * w0v[nt];
                p1[r] += h * w1v[nt];
            }
        }
        // reduce over the 16 feat-lanes (xor within 16-lane group)
#pragma unroll
        for (int off = 1; off < 16; off <<= 1) {
#pragma unroll
            for (int r = 0; r < 4; r++) {
                p0[r] += __shfl_xor(p0[r], off);
                p1[r] += __shfl_xor(p1[r], off);
            }
        }
        if (fr == 0) {
#pragma unroll
            for (int r = 0; r < 4; r++) {
                int node = node0 + rt * 16 + fq * 4 + r;
                if (node < N_NODES) {
                    float2 o;
                    o.x = 1.f / (1.f + expf(-(p0[r] + b0)));
                    o.y = 1.f / (1.f + expf(-(p1[r] + b1)));
                    *(float2*)(out + (size_t)node * NCLASS) = o;
                }
            }
        }
    }
}

extern "C" void kernel_launch(void* const* d_in, const int* in_sizes, int n_in,
                              void* d_out, int out_size, void* d_ws, size_t ws_size,
                              hipStream_t stream) {
    const float* in_feat = (const float*)d_in[0];
    const int*   src     = (const int*)d_in[1];
    const int*   dst     = (const int*)d_in[2];
    const float* Wself   = (const float*)d_in[3];
    const float* Wneigh  = (const float*)d_in[4];
    const float* bneigh  = (const float*)d_in[5];
    const float* Wfc     = (const float*)d_in[6];
    const float* bfc     = (const float*)d_in[7];
    float* out = (float*)d_out;

    // ---- workspace layout (all 16B-aligned) ----
    int* degi   = (int*)d_ws;                        // [50000]
    int* offs   = degi + N_NODES;                    // [50001]
    int* cursor = offs + N_NODES + 1;                // [50000]
    int* eidx   = cursor + N_NODES;                  // [800000]
    size_t int_elems = (size_t)N_NODES * 3 + 1 + N_EDGES;    // 950001
    int_elems = (int_elems + 3) & ~(size_t)3;                // 950004 -> 16B aligned
    unsigned short* xh   = (unsigned short*)((int*)d_ws + int_elems);  // [50000*128] bf16
    unsigned short* wcat = xh + (size_t)N_NODES * FEATS;               // [128*256] bf16
    unsigned short* hh   = wcat + (size_t)FEATS * KTOT;                // [50000*128] bf16

    hipMemsetAsync(d_ws, 0, (size_t)N_NODES * sizeof(int), stream);

    prep<<<CASTX_BLOCKS + HIST_BLOCKS + CASTW_BLOCKS, 256, 0, stream>>>(
        in_feat, dst, Wself, Wneigh, xh, wcat, degi);
    scan_offsets<<<1, SCAN_T, 0, stream>>>(degi, offs, cursor);
    int eb = (N_EDGES + 255) / 256;
    scatter_idx<<<eb, 256, 0, stream>>>(src, dst, cursor, eidx);

    int gb = (N_NODES + 3) / 4;
    gather_mean<<<gb, 256, 0, stream>>>((const unsigned*)xh, eidx, offs,
                                        (unsigned*)hh);

    int nb = (N_NODES + 127) / 128;
    node_mfma<<<nb, 256, 0, stream>>>(xh, hh, wcat, bneigh, Wfc, bfc, out);
}

// Round 4
// 229.646 us; speedup vs baseline: 6.8963x; 1.4520x over previous
//
#include <hip/hip_runtime.h>
#include <math.h>

#define N_NODES 50000
#define N_EDGES 800000
#define FEATS 128
#define KTOT 256
#define NCLASS 2
#define NSB 196   // scan blocks: ceil(50000/256)

typedef __attribute__((ext_vector_type(8))) short bf16x8;
typedef __attribute__((ext_vector_type(4))) float f32x4;

__device__ __forceinline__ float bflo(unsigned u) {
    return __uint_as_float(u << 16);
}
__device__ __forceinline__ float bfhi(unsigned u) {
    return __uint_as_float(u & 0xffff0000u);
}
// round-to-nearest-even f32 -> bf16 (inputs finite)
__device__ __forceinline__ unsigned f2bf(float f) {
    unsigned u = __float_as_uint(f);
    return (u + 0x7fffu + ((u >> 16) & 1u)) >> 16;
}

// ---------- 1. fused prep: cast x->bf16, cast [Ws|Wn]->bf16 Wcat[N][K],
//                degree histogram (all independent) -------------------------
#define CASTX_BLOCKS 3125   // 6.4M floats / (256 thr * 8)
#define HIST_BLOCKS  3125   // 800000 / 256
#define CASTW_BLOCKS 64     // 32768 elems / (256 thr * 2)

__global__ __launch_bounds__(256) void prep(
    const float* __restrict__ x, const int* __restrict__ dst,
    const float* __restrict__ Ws, const float* __restrict__ Wn,
    unsigned short* __restrict__ xh, unsigned short* __restrict__ wcat,
    int* __restrict__ degi)
{
    int b = blockIdx.x;
    if (b < CASTX_BLOCKS) {
        size_t i = ((size_t)b * 256 + threadIdx.x) * 8;
        float4 v0 = *(const float4*)(x + i);
        float4 v1 = *(const float4*)(x + i + 4);
        uint4 o;
        o.x = f2bf(v0.x) | (f2bf(v0.y) << 16);
        o.y = f2bf(v0.z) | (f2bf(v0.w) << 16);
        o.z = f2bf(v1.x) | (f2bf(v1.y) << 16);
        o.w = f2bf(v1.z) | (f2bf(v1.w) << 16);
        *(uint4*)(xh + i) = o;
    } else if (b < CASTX_BLOCKS + HIST_BLOCKS) {
        int e = (b - CASTX_BLOCKS) * 256 + threadIdx.x;
        if (e < N_EDGES) atomicAdd(&degi[dst[e]], 1);
    } else {
        int i = (b - CASTX_BLOCKS - HIST_BLOCKS) * 512 + threadIdx.x * 2;
        int n = i >> 8, k = i & 255;          // k is even
        float a0 = (k < 128) ? Ws[n * 128 + k] : Wn[n * 128 + k - 128];
        float a1 = (k + 1 < 128) ? Ws[n * 128 + k + 1] : Wn[n * 128 + k + 1 - 128];
        *(unsigned*)(wcat + i) = f2bf(a0) | (f2bf(a1) << 16);
    }
}

// ---------- 2a. per-block inclusive scan of degrees ---------------------------
__global__ __launch_bounds__(256) void scan1(
    const int* __restrict__ degi, int* __restrict__ incl, int* __restrict__ bsum)
{
    __shared__ int sh[256];
    const int t = threadIdx.x;
    const int i = blockIdx.x * 256 + t;
    int d = (i < N_NODES) ? degi[i] : 0;
    sh[t] = d;
    __syncthreads();
#pragma unroll
    for (int off = 1; off < 256; off <<= 1) {
        int v = sh[t];
        int u = (t >= off) ? sh[t - off] : 0;
        __syncthreads();
        sh[t] = v + u;
        __syncthreads();
    }
    int iv = sh[t];
    if (i < N_NODES) incl[i] = iv;
    if (t == 255) bsum[blockIdx.x] = iv;
}

// ---------- 2b. add block offsets, emit offs + cursor -------------------------
// Each block re-derives its own prefix from bsum[0..b-1] (196 ints, L2-hot).
__global__ __launch_bounds__(256) void scan2(
    const int* __restrict__ degi, const int* __restrict__ incl,
    const int* __restrict__ bsum, int* __restrict__ offs, int* __restrict__ cursor)
{
    __shared__ int sh[256];
    const int t = threadIdx.x;
    const int b = blockIdx.x;
    sh[t] = (t < b) ? bsum[t] : 0;
    __syncthreads();
#pragma unroll
    for (int off = 128; off > 0; off >>= 1) {
        if (t < off) sh[t] += sh[t + off];
        __syncthreads();
    }
    const int bo = sh[0];
    const int i = b * 256 + t;
    if (i < N_NODES) {
        int o = bo + incl[i] - degi[i];
        offs[i] = o;
        cursor[i] = o;
    }
    if (b == 0 && t == 0) offs[N_NODES] = N_EDGES;
}

// ---------- 3. scatter src into per-dst buckets ------------------------------
__global__ __launch_bounds__(256) void scatter_idx(
    const int* __restrict__ src, const int* __restrict__ dst,
    int* __restrict__ cursor, int* __restrict__ eidx)
{
    int e = blockIdx.x * 256 + threadIdx.x;
    if (e < N_EDGES) {
        int pos = atomicAdd(&cursor[dst[e]], 1);
        eidx[pos] = src[e];
    }
}

// ---------- 4. per-node gather + mean over bf16 rows -------------------------
// One wave per node, lane owns 1 uint (2 bf16 cols). 256 B/row coalesced.
__global__ __launch_bounds__(256) void gather_mean(
    const unsigned* __restrict__ xh32, const int* __restrict__ eidx,
    const int* __restrict__ offs, unsigned* __restrict__ hh32)
{
    int node = blockIdx.x * 4 + (threadIdx.x >> 6);
    if (node >= N_NODES) return;
    const int l = threadIdx.x & 63;
    const int beg = offs[node];
    const int end = offs[node + 1];

    float s0 = 0.f, s1 = 0.f, t0 = 0.f, t1 = 0.f;
    int e = beg;
    for (; e + 3 < end; e += 4) {
        unsigned u0 = xh32[(size_t)eidx[e]     * 64 + l];
        unsigned u1 = xh32[(size_t)eidx[e + 1] * 64 + l];
        unsigned u2 = xh32[(size_t)eidx[e + 2] * 64 + l];
        unsigned u3 = xh32[(size_t)eidx[e + 3] * 64 + l];
        s0 += bflo(u0) + bflo(u1);
        s1 += bfhi(u0) + bfhi(u1);
        t0 += bflo(u2) + bflo(u3);
        t1 += bfhi(u2) + bfhi(u3);
    }
    for (; e < end; e++) {
        unsigned u = xh32[(size_t)eidx[e] * 64 + l];
        s0 += bflo(u);
        s1 += bfhi(u);
    }
    const float r = 1.0f / fmaxf((float)(end - beg), 1.0f);
    hh32[(size_t)node * 64 + l] = f2bf((s0 + t0) * r) | (f2bf((s1 + t1) * r) << 16);
}

// ---------- 5. node MFMA: h=relu([xh|hh]@Wcat^T+bn); out=sigmoid(h@Wfc^T+bfc)
// 4 waves/block, 32 nodes/wave. A = [nodes][K] row-major (xh k<128, hh
// k>=128); B = Wcat [N][K] (B^T layout, m91 recipe). D: col=l&15 (feat),
// row=(l>>4)*4+reg (node) [m89-verified].
__global__ __launch_bounds__(256) void node_mfma(
    const unsigned short* __restrict__ xh, const unsigned short* __restrict__ hh,
    const unsigned short* __restrict__ wcat,
    const float* __restrict__ bn, const float* __restrict__ wfc,
    const float* __restrict__ bfc, float* __restrict__ out)
{
    const int wid = threadIdx.x >> 6;
    const int l = threadIdx.x & 63;
    const int node0 = blockIdx.x * 128 + wid * 32;
    const int fr = l & 15, fq = l >> 4;

    float bnv[8], w0v[8], w1v[8];
#pragma unroll
    for (int nt = 0; nt < 8; nt++) {
        int f = nt * 16 + fr;
        bnv[nt] = bn[f];
        w0v[nt] = wfc[f];
        w1v[nt] = wfc[FEATS + f];
    }

    f32x4 acc[2][8] = {};   // [row-tile][n-tile]

#pragma unroll
    for (int ks = 0; ks < 8; ks++) {
        const unsigned short* abase = (ks < 4) ? xh : hh;
        const int ka = (ks & 3) * 32 + fq * 8;
        const int kb = ks * 32 + fq * 8;

        bf16x8 bfr[8];
#pragma unroll
        for (int nt = 0; nt < 8; nt++) {
            int n = nt * 16 + fr;
            bfr[nt] = *(const bf16x8*)(wcat + (size_t)n * KTOT + kb);
        }
#pragma unroll
        for (int rt = 0; rt < 2; rt++) {
            int row = node0 + rt * 16 + fr;
            row = (row < N_NODES) ? row : N_NODES - 1;   // clamp; stores guarded
            bf16x8 afr = *(const bf16x8*)(abase + (size_t)row * FEATS + ka);
#pragma unroll
            for (int nt = 0; nt < 8; nt++)
                acc[rt][nt] = __builtin_amdgcn_mfma_f32_16x16x32_bf16(
                    afr, bfr[nt], acc[rt][nt], 0, 0, 0);
        }
    }

    const float b0 = bfc[0], b1 = bfc[1];
#pragma unroll
    for (int rt = 0; rt < 2; rt++) {
        float p0[4] = {0, 0, 0, 0}, p1[4] = {0, 0, 0, 0};
#pragma unroll
        for (int nt = 0; nt < 8; nt++) {
#pragma unroll
            for (int r = 0; r < 4; r++) {
                float h = fmaxf(acc[rt][nt][r] + bnv[nt], 0.f);
                p0[r] += h * w0v[nt];
                p1[r] += h * w1v[nt];
            }
        }
#pragma unroll
        for (int off = 1; off < 16; off <<= 1) {
#pragma unroll
            for (int r = 0; r < 4; r++) {
                p0[r] += __shfl_xor(p0[r], off);
                p1[r] += __shfl_xor(p1[r], off);
            }
        }
        if (fr == 0) {
#pragma unroll
            for (int r = 0; r < 4; r++) {
                int node = node0 + rt * 16 + fq * 4 + r;
                if (node < N_NODES) {
                    float2 o;
                    o.x = 1.f / (1.f + expf(-(p0[r] + b0)));
                    o.y = 1.f / (1.f + expf(-(p1[r] + b1)));
                    *(float2*)(out + (size_t)node * NCLASS) = o;
                }
            }
        }
    }
}

extern "C" void kernel_launch(void* const* d_in, const int* in_sizes, int n_in,
                              void* d_out, int out_size, void* d_ws, size_t ws_size,
                              hipStream_t stream) {
    const float* in_feat = (const float*)d_in[0];
    const int*   src     = (const int*)d_in[1];
    const int*   dst     = (const int*)d_in[2];
    const float* Wself   = (const float*)d_in[3];
    const float* Wneigh  = (const float*)d_in[4];
    const float* bneigh  = (const float*)d_in[5];
    const float* Wfc     = (const float*)d_in[6];
    const float* bfc     = (const float*)d_in[7];
    float* out = (float*)d_out;

    // ---- workspace layout (all 16B-aligned) ----
    int* degi   = (int*)d_ws;                        // [50000]
    int* offs   = degi + N_NODES;                    // [50001]
    int* cursor = offs + N_NODES + 1;                // [50000]
    int* eidx   = cursor + N_NODES;                  // [800000]
    int* incl   = eidx + N_EDGES;                    // [50000]
    int* bsum   = incl + N_NODES;                    // [256]
    size_t int_elems = (size_t)N_NODES * 4 + 1 + N_EDGES + 256;   // 1000257
    int_elems = (int_elems + 3) & ~(size_t)3;                      // 16B aligned
    unsigned short* xh   = (unsigned short*)((int*)d_ws + int_elems);  // bf16 [50000*128]
    unsigned short* wcat = xh + (size_t)N_NODES * FEATS;               // bf16 [128*256]
    unsigned short* hh   = wcat + (size_t)FEATS * KTOT;                // bf16 [50000*128]

    hipMemsetAsync(d_ws, 0, (size_t)N_NODES * sizeof(int), stream);

    prep<<<CASTX_BLOCKS + HIST_BLOCKS + CASTW_BLOCKS, 256, 0, stream>>>(
        in_feat, dst, Wself, Wneigh, xh, wcat, degi);

    scan1<<<NSB, 256, 0, stream>>>(degi, incl, bsum);
    scan2<<<NSB, 256, 0, stream>>>(degi, incl, bsum, offs, cursor);

    int eb = (N_EDGES + 255) / 256;
    scatter_idx<<<eb, 256, 0, stream>>>(src, dst, cursor, eidx);

    int gb = (N_NODES + 3) / 4;
    gather_mean<<<gb, 256, 0, stream>>>((const unsigned*)xh, eidx, offs,
                                        (unsigned*)hh);

    int nb = (N_NODES + 127) / 128;
    node_mfma<<<nb, 256, 0, stream>>>(xh, hh, wcat, bneigh, Wfc, bfc, out);
}

// Round 7
// 227.339 us; speedup vs baseline: 6.9663x; 1.0101x over previous
//
#include <hip/hip_runtime.h>
#include <math.h>

#define N_NODES 50000
#define N_EDGES 800000
#define FEATS 128
#define KTOT 256
#define NCLASS 2
#define NSB 196        // scan blocks: ceil(50000/256)
#define NXCD 8
#define DRANGE 6250    // N_NODES / NXCD
#define SC_CHUNKS 384  // edge chunks per dst-range pass

typedef __attribute__((ext_vector_type(8))) short bf16x8;
typedef __attribute__((ext_vector_type(4))) float f32x4;

__device__ __forceinline__ float bflo(unsigned u) {
    return __uint_as_float(u << 16);
}
__device__ __forceinline__ float bfhi(unsigned u) {
    return __uint_as_float(u & 0xffff0000u);
}
// round-to-nearest-even f32 -> bf16 (inputs finite)
__device__ __forceinline__ unsigned f2bf(float f) {
    unsigned u = __float_as_uint(f);
    return (u + 0x7fffu + ((u >> 16) & 1u)) >> 16;
}

// ---------- 1. fused prep: cast x->bf16, cast [Ws|Wn]->bf16 Wcat[N][K],
//                degree histogram (all independent) -------------------------
#define CASTX_BLOCKS 3125   // 6.4M floats / (256 thr * 8)
#define HIST_BLOCKS  3125   // 800000 / 256
#define CASTW_BLOCKS 64     // 32768 elems / (256 thr * 2)

__global__ __launch_bounds__(256) void prep(
    const float* __restrict__ x, const int* __restrict__ dst,
    const float* __restrict__ Ws, const float* __restrict__ Wn,
    unsigned short* __restrict__ xh, unsigned short* __restrict__ wcat,
    int* __restrict__ degi)
{
    int b = blockIdx.x;
    if (b < CASTX_BLOCKS) {
        size_t i = ((size_t)b * 256 + threadIdx.x) * 8;
        float4 v0 = *(const float4*)(x + i);
        float4 v1 = *(const float4*)(x + i + 4);
        uint4 o;
        o.x = f2bf(v0.x) | (f2bf(v0.y) << 16);
        o.y = f2bf(v0.z) | (f2bf(v0.w) << 16);
        o.z = f2bf(v1.x) | (f2bf(v1.y) << 16);
        o.w = f2bf(v1.z) | (f2bf(v1.w) << 16);
        *(uint4*)(xh + i) = o;
    } else if (b < CASTX_BLOCKS + HIST_BLOCKS) {
        int e = (b - CASTX_BLOCKS) * 256 + threadIdx.x;
        if (e < N_EDGES) atomicAdd(&degi[dst[e]], 1);
    } else {
        int i = (b - CASTX_BLOCKS - HIST_BLOCKS) * 512 + threadIdx.x * 2;
        int n = i >> 8, k = i & 255;          // k is even
        float a0 = (k < 128) ? Ws[n * 128 + k] : Wn[n * 128 + k - 128];
        float a1 = (k + 1 < 128) ? Ws[n * 128 + k + 1] : Wn[n * 128 + k + 1 - 128];
        *(unsigned*)(wcat + i) = f2bf(a0) | (f2bf(a1) << 16);
    }
}

// ---------- 2a. per-block inclusive scan of degrees ---------------------------
__global__ __launch_bounds__(256) void scan1(
    const int* __restrict__ degi, int* __restrict__ incl, int* __restrict__ bsum)
{
    __shared__ int sh[256];
    const int t = threadIdx.x;
    const int i = blockIdx.x * 256 + t;
    int d = (i < N_NODES) ? degi[i] : 0;
    sh[t] = d;
    __syncthreads();
#pragma unroll
    for (int off = 1; off < 256; off <<= 1) {
        int v = sh[t];
        int u = (t >= off) ? sh[t - off] : 0;
        __syncthreads();
        sh[t] = v + u;
        __syncthreads();
    }
    int iv = sh[t];
    if (i < N_NODES) incl[i] = iv;
    if (t == 255) bsum[blockIdx.x] = iv;
}

// ---------- 2b. add block offsets, emit offs + cursor -------------------------
__global__ __launch_bounds__(256) void scan2(
    const int* __restrict__ degi, const int* __restrict__ incl,
    const int* __restrict__ bsum, int* __restrict__ offs, int* __restrict__ cursor)
{
    __shared__ int sh[256];
    const int t = threadIdx.x;
    const int b = blockIdx.x;
    sh[t] = (t < b) ? bsum[t] : 0;
    __syncthreads();
#pragma unroll
    for (int off = 128; off > 0; off >>= 1) {
        if (t < off) sh[t] += sh[t + off];
        __syncthreads();
    }
    const int bo = sh[0];
    const int i = b * 256 + t;
    if (i < N_NODES) {
        int o = bo + incl[i] - degi[i];
        offs[i] = o;
        cursor[i] = o;
    }
    if (b == 0 && t == 0) offs[N_NODES] = N_EDGES;
}

// ---------- 3. XCD-local scatter of src into per-dst buckets ------------------
// blockIdx%8 -> XCD r handles only dst range [r*6250, (r+1)*6250). Each range
// pass re-scans the edge stream (dst re-reads are L3-hot). All eidx/cursor
// lines for a range are written by ONE XCD -> stay L2-resident, write back
// once (vs 64B write-through per 4B edge write before).
__global__ __launch_bounds__(256) void scatter_idx(
    const int* __restrict__ src, const int* __restrict__ dst,
    int* __restrict__ cursor, int* __restrict__ eidx)
{
    const int r = blockIdx.x & (NXCD - 1);
    const int c = blockIdx.x >> 3;
    const int lo = r * DRANGE;
    const int hi = lo + DRANGE;          // N_NODES = 8*6250 exactly
    const int CH = (N_EDGES + SC_CHUNKS - 1) / SC_CHUNKS;   // 2084
    const int ebeg = c * CH;
    const int eend = (ebeg + CH < N_EDGES) ? ebeg + CH : N_EDGES;

    for (int e = ebeg + threadIdx.x; e < eend; e += 256) {
        int d = dst[e];
        if (d >= lo && d < hi) {
            int pos = atomicAdd(&cursor[d], 1);
            eidx[pos] = src[e];
        }
    }
}

// ---------- 4. per-node gather + mean over bf16 rows -------------------------
// One wave per node, lane owns 1 uint (2 bf16 cols). 256 B/row coalesced.
__global__ __launch_bounds__(256) void gather_mean(
    const unsigned* __restrict__ xh32, const int* __restrict__ eidx,
    const int* __restrict__ offs, unsigned* __restrict__ hh32)
{
    int node = blockIdx.x * 4 + (threadIdx.x >> 6);
    if (node >= N_NODES) return;
    const int l = threadIdx.x & 63;
    const int beg = offs[node];
    const int end = offs[node + 1];

    float s0 = 0.f, s1 = 0.f, t0 = 0.f, t1 = 0.f;
    int e = beg;
    for (; e + 3 < end; e += 4) {
        unsigned u0 = xh32[(size_t)eidx[e]     * 64 + l];
        unsigned u1 = xh32[(size_t)eidx[e + 1] * 64 + l];
        unsigned u2 = xh32[(size_t)eidx[e + 2] * 64 + l];
        unsigned u3 = xh32[(size_t)eidx[e + 3] * 64 + l];
        s0 += bflo(u0) + bflo(u1);
        s1 += bfhi(u0) + bfhi(u1);
        t0 += bflo(u2) + bflo(u3);
        t1 += bfhi(u2) + bfhi(u3);
    }
    for (; e < end; e++) {
        unsigned u = xh32[(size_t)eidx[e] * 64 + l];
        s0 += bflo(u);
        s1 += bfhi(u);
    }
    const float r = 1.0f / fmaxf((float)(end - beg), 1.0f);
    hh32[(size_t)node * 64 + l] = f2bf((s0 + t0) * r) | (f2bf((s1 + t1) * r) << 16);
}

// ---------- 5. node MFMA: h=relu([xh|hh]@Wcat^T+bn); out=sigmoid(h@Wfc^T+bfc)
__global__ __launch_bounds__(256) void node_mfma(
    const unsigned short* __restrict__ xh, const unsigned short* __restrict__ hh,
    const unsigned short* __restrict__ wcat,
    const float* __restrict__ bn, const float* __restrict__ wfc,
    const float* __restrict__ bfc, float* __restrict__ out)
{
    const int wid = threadIdx.x >> 6;
    const int l = threadIdx.x & 63;
    const int node0 = blockIdx.x * 128 + wid * 32;
    const int fr = l & 15, fq = l >> 4;

    float bnv[8], w0v[8], w1v[8];
#pragma unroll
    for (int nt = 0; nt < 8; nt++) {
        int f = nt * 16 + fr;
        bnv[nt] = bn[f];
        w0v[nt] = wfc[f];
        w1v[nt] = wfc[FEATS + f];
    }

    f32x4 acc[2][8] = {};   // [row-tile][n-tile]

#pragma unroll
    for (int ks = 0; ks < 8; ks++) {
        const unsigned short* abase = (ks < 4) ? xh : hh;
        const int ka = (ks & 3) * 32 + fq * 8;
        const int kb = ks * 32 + fq * 8;

        bf16x8 bfr[8];
#pragma unroll
        for (int nt = 0; nt < 8; nt++) {
            int n = nt * 16 + fr;
            bfr[nt] = *(const bf16x8*)(wcat + (size_t)n * KTOT + kb);
        }
#pragma unroll
        for (int rt = 0; rt < 2; rt++) {
            int row = node0 + rt * 16 + fr;
            row = (row < N_NODES) ? row : N_NODES - 1;   // clamp; stores guarded
            bf16x8 afr = *(const bf16x8*)(abase + (size_t)row * FEATS + ka);
#pragma unroll
            for (int nt = 0; nt < 8; nt++)
                acc[rt][nt] = __builtin_amdgcn_mfma_f32_16x16x32_bf16(
                    afr, bfr[nt], acc[rt][nt], 0, 0, 0);
        }
    }

    const float b0 = bfc[0], b1 = bfc[1];
#pragma unroll
    for (int rt = 0; rt < 2; rt++) {
        float p0[4] = {0, 0, 0, 0}, p1[4] = {0, 0, 0, 0};
#pragma unroll
        for (int nt = 0; nt < 8; nt++) {
#pragma unroll
            for (int r = 0; r < 4; r++) {
                float h = fmaxf(acc[rt][nt][r] + bnv[nt], 0.f);
                p0[r] += h * w0v[nt];
                p1[r] += h * w1v[nt];
            }
        }
#pragma unroll
        for (int off = 1; off < 16; off <<= 1) {
#pragma unroll
            for (int r = 0; r < 4; r++) {
                p0[r] += __shfl_xor(p0[r], off);
                p1[r] += __shfl_xor(p1[r], off);
            }
        }
        if (fr == 0) {
#pragma unroll
            for (int r = 0; r < 4; r++) {
                int node = node0 + rt * 16 + fq * 4 + r;
                if (node < N_NODES) {
                    float2 o;
                    o.x = 1.f / (1.f + expf(-(p0[r] + b0)));
                    o.y = 1.f / (1.f + expf(-(p1[r] + b1)));
                    *(float2*)(out + (size_t)node * NCLASS) = o;
                }
            }
        }
    }
}

extern "C" void kernel_launch(void* const* d_in, const int* in_sizes, int n_in,
                              void* d_out, int out_size, void* d_ws, size_t ws_size,
                              hipStream_t stream) {
    const float* in_feat = (const float*)d_in[0];
    const int*   src     = (const int*)d_in[1];
    const int*   dst     = (const int*)d_in[2];
    const float* Wself   = (const float*)d_in[3];
    const float* Wneigh  = (const float*)d_in[4];
    const float* bneigh  = (const float*)d_in[5];
    const float* Wfc     = (const float*)d_in[6];
    const float* bfc     = (const float*)d_in[7];
    float* out = (float*)d_out;

    // ---- workspace layout (all 16B-aligned) ----
    int* degi   = (int*)d_ws;                        // [50000]
    int* offs   = degi + N_NODES;                    // [50001]
    int* cursor = offs + N_NODES + 1;                // [50000]
    int* eidx   = cursor + N_NODES;                  // [800000]
    int* incl   = eidx + N_EDGES;                    // [50000]
    int* bsum   = incl + N_NODES;                    // [256]
    size_t int_elems = (size_t)N_NODES * 4 + 1 + N_EDGES + 256;
    int_elems = (int_elems + 3) & ~(size_t)3;        // 16B aligned
    unsigned short* xh   = (unsigned short*)((int*)d_ws + int_elems);  // bf16 [50000*128]
    unsigned short* wcat = xh + (size_t)N_NODES * FEATS;               // bf16 [128*256]
    unsigned short* hh   = wcat + (size_t)FEATS * KTOT;                // bf16 [50000*128]

    hipMemsetAsync(d_ws, 0, (size_t)N_NODES * sizeof(int), stream);

    prep<<<CASTX_BLOCKS + HIST_BLOCKS + CASTW_BLOCKS, 256, 0, stream>>>(
        in_feat, dst, Wself, Wneigh, xh, wcat, degi);

    scan1<<<NSB, 256, 0, stream>>>(degi, incl, bsum);
    scan2<<<NSB, 256, 0, stream>>>(degi, incl, bsum, offs, cursor);

    scatter_idx<<<NXCD * SC_CHUNKS, 256, 0, stream>>>(src, dst, cursor, eidx);

    int gb = (N_NODES + 3) / 4;
    gather_mean<<<gb, 256, 0, stream>>>((const unsigned*)xh, eidx, offs,
                                        (unsigned*)hh);

    int nb = (N_NODES + 127) / 128;
    node_mfma<<<nb, 256, 0, stream>>>(xh, hh, wcat, bneigh, Wfc, bfc, out);
}